// Round 19
// baseline (397.372 us; speedup 1.0000x reference)
//
#include <hip/hip_runtime.h>

typedef unsigned short ushortT;
typedef unsigned int uintT;
typedef __bf16 bf16x8 __attribute__((ext_vector_type(8)));
typedef short short8v __attribute__((ext_vector_type(8)));
typedef float f32x4 __attribute__((ext_vector_type(4)));
typedef float float4v __attribute__((ext_vector_type(4)));

#define DEV __device__ __forceinline__

DEV float sigmoidf_(float x) { return 1.f / (1.f + __expf(-x)); }
DEV float siluf_(float x)    { return x * sigmoidf_(x); }
DEV float softplusf_(float x){ return fmaxf(x, 0.f) + log1pf(__expf(-fabsf(x))); }

// native RTNE bf16 convert
DEV ushortT f2bf(float f) {
  __bf16 h = (__bf16)f;
  return __builtin_bit_cast(ushortT, h);
}
DEV float bf2f(ushortT h) {
  union { uintT u; float f; } x; x.u = ((uintT)h) << 16;
  return x.f;
}

// async global->LDS, 16 bytes/lane
typedef const __attribute__((address_space(1))) uintT guintT;
typedef __attribute__((address_space(3))) uintT luintT;
DEV void gl16(const void* g, void* l) {
  __builtin_amdgcn_global_load_lds((guintT*)g, (luintT*)l, 16, 0, 0);
}

// scan-pos -> image-pos within one 4096 sequence
DEV int natimg(int dir, int l) {
  if (dir == 0) return l;
  if (dir == 1) return 4095 - l;
  int s = (dir == 2) ? l : (4095 - l);
  return ((s & 63) << 6) | (s >> 6);
}
// local window scan idx m (0..16383) -> natural row
DEV int natwin(int m) {
  int b = m >> 12, ih = (m >> 9) & 7, iw = (m >> 6) & 7, p = (m >> 3) & 7, q = m & 7;
  return (b << 12) | ((((ih << 3) | p) << 6) | ((iw << 3) | q));
}

// ---------------- LayerNorm over C (NCHW in -> NHWC bf16 out) ----------------
__global__ __launch_bounds__(256)
void ln_kernel(const float* __restrict__ x, const float* __restrict__ g,
               const float* __restrict__ b, ushortT* __restrict__ xn) {
  const int C = 192, HW = 4096;
  __shared__ float tile[64][193];
  __shared__ float red[2][4][64];
  __shared__ float mean_s[64], rstd_s[64];
  int bb = blockIdx.x >> 6;
  int p0 = (blockIdx.x & 63) << 6;
  int tid = threadIdx.x;
  int p = tid & 63, c4 = tid >> 6;
  for (int c = c4; c < C; c += 4)
    tile[p][c] = x[((size_t)(bb * C + c)) * HW + p0 + p];
  __syncthreads();
  float s = 0.f, s2 = 0.f;
  for (int c = c4 * 48; c < c4 * 48 + 48; ++c) { float v = tile[p][c]; s += v; s2 += v * v; }
  red[0][c4][p] = s; red[1][c4][p] = s2;
  __syncthreads();
  if (c4 == 0) {
    float ss = red[0][0][p] + red[0][1][p] + red[0][2][p] + red[0][3][p];
    float qq = red[1][0][p] + red[1][1][p] + red[1][2][p] + red[1][3][p];
    float m = ss * (1.f / 192.f);
    float var = qq * (1.f / 192.f) - m * m;
    mean_s[p] = m;
    rstd_s[p] = rsqrtf(var + 1e-5f);
  }
  __syncthreads();
  for (int e = tid; e < 64 * 192; e += 256) {
    int pp = e / 192, c = e % 192;
    xn[((size_t)bb * HW + p0 + pp) * C + c] =
        f2bf((tile[pp][c] - mean_s[pp]) * rstd_s[pp] * g[c] + b[c]);
  }
}

// ---------------- weight prep (bf16 [N][K]) ----------------
__global__ __launch_bounds__(256)
void prep_w(const float* __restrict__ r_in_w, const float* __restrict__ r_xproj_w,
            const float* __restrict__ r_out_w, const float* __restrict__ l_in_w,
            const float* __restrict__ l_xproj_w, const float* __restrict__ l_out_w,
            const float* __restrict__ c1_w, const float* __restrict__ c2_w,
            ushortT* __restrict__ wbf) {
  int i = blockIdx.x * 256 + threadIdx.x;
  if (i >= 813312) return;
  float v;
  if (i < 294912) {
    int d = i / 73728, j = i % 73728, n = j / 192, k = j % 192;
    v = r_in_w[(size_t)d * 73728 + k * 384 + n];
  } else if (i < 328704) {
    int j = i - 294912; int d = j / 8448, jj = j % 8448, n = jj / 192, k = jj % 192;
    v = r_xproj_w[(size_t)d * 8448 + k * 44 + n];
  } else if (i < 476160) {
    int j = i - 328704; int d = j / 36864, jj = j % 36864, n = jj / 192, k = jj % 192;
    v = r_out_w[(size_t)d * 36864 + k * 192 + n];
  } else if (i < 549888) {
    int j = i - 476160; int n = j / 192, k = j % 192;
    v = l_in_w[k * 384 + n];
  } else if (i < 555264) {
    int j = i - 549888; int n = j / 192, k = j % 192;
    v = l_xproj_w[k * 28 + n];
  } else if (i < 592128) {
    int j = i - 555264; int n = j / 192, k = j % 192;
    v = l_out_w[k * 192 + n];
  } else if (i < 739584) {
    v = c1_w[i - 592128];
  } else {
    v = c2_w[i - 739584];
  }
  wbf[i] = f2bf(v);
}

// ---------------- fused xproj(B,C)+dt weights ----------------
__global__ __launch_bounds__(256)
void prep_wxpc(const float* __restrict__ r_xproj_w, const float* __restrict__ r_dt_w,
               const float* __restrict__ l_xproj_w, const float* __restrict__ l_dt_w,
               ushortT* __restrict__ wxpc) {
  int i = blockIdx.x * 256 + threadIdx.x;
  if (i >= 211968) return;
  float v;
  if (i < 172032) {
    int d = i / 43008, j = i % 43008, n = j / 192, k = j % 192;
    if (n < 32) v = r_xproj_w[(size_t)d * 8448 + k * 44 + 12 + n];
    else {
      int np = n - 32;
      v = 0.f;
#pragma unroll
      for (int r = 0; r < 12; ++r)
        v += r_xproj_w[(size_t)d * 8448 + k * 44 + r] * r_dt_w[(size_t)d * 2304 + r * 192 + np];
    }
  } else {
    int j = i - 172032, n = j / 192, k = j % 192;
    if (n < 16) v = l_xproj_w[k * 28 + 12 + n];
    else {
      int np = n - 16;
      v = 0.f;
#pragma unroll
      for (int r = 0; r < 12; ++r)
        v += l_xproj_w[k * 28 + r] * l_dt_w[r * 192 + np];
    }
  }
  wxpc[i] = f2bf(v);
}

// ---------------- conv/dw weight transposes ----------------
__global__ __launch_bounds__(256)
void prep_cw(const float* __restrict__ dw_w, const float* __restrict__ r_conv_w,
             const float* __restrict__ l_conv_w, float* __restrict__ cwt) {
  int i = blockIdx.x * 256 + threadIdx.x;
  if (i < 6912) {
    int ch = i / 9, tap = i % 9;
    cwt[tap * 768 + ch] = dw_w[i];
  } else if (i < 6912 + 3072) {
    int j = i - 6912; int d = j / 768, ch = (j % 768) / 4, k = j & 3;
    cwt[6912 + (d * 4 + k) * 192 + ch] = r_conv_w[j];
  } else if (i < 6912 + 3072 + 384) {
    int j = i - 6912 - 3072; int ch = j >> 1, k = j & 1;
    cwt[9984 + k * 192 + ch] = l_conv_w[j];
  }
}

// ---------------- MFMA bf16 GEMM (natural A, gload_lds, hoisted addressing) ----------------
// EPI 0 fp32+bias; 1 bf16+bias; 2 split N=384; 3 xproj+dt (split, dd bf16);
// 5 split 4-dir N=1536; 6 bf16 accumulate; 7 bf16 scaled (0.25*bias[0]).
// CHUNK=1: A,B chunk-major over 192-wide K chunks.
// TPB: threads/block (256 -> BM=64, 4 waves; 512 -> BM=128, 8 waves). MF=2 always.
template <int EPI, int BM, int CHUNK, int TPB>
__global__ __launch_bounds__(TPB)
void gemm_mfma(const void* __restrict__ Ap, const ushortT* __restrict__ Bw,
               const float* __restrict__ bias, void* __restrict__ C1,
               void* __restrict__ C2, int M, int N, int K, int nGc, int cpb,
               int tilesPerDir, size_t aStr, size_t bStr, size_t c1Str, size_t c2Str,
               int split) {
  const size_t BLC = (size_t)4 * 4096 * 192;
  __shared__ __align__(16) ushortT As[BM * 192];
  __shared__ __align__(16) ushortT Bs[64 * 192];
  int nwg = gridDim.x;
  int bid = blockIdx.x;
  int q = nwg >> 3, r = nwg & 7, xq = bid & 7, o = bid >> 3;
  int wg = (xq < r ? xq * (q + 1) : r * (q + 1) + (xq - r) * q) + o;
  int d = wg / tilesPerDir;
  wg -= d * tilesPerDir;
  int rt = wg / nGc, cg = wg % nGc;
  int bm = rt * BM;
  int tid = threadIdx.x;
  int lane = tid & 63, w = tid >> 6;
  constexpr int MF = 2;
  constexpr int SLOTS_A = BM * 24 / TPB;   // 6
  constexpr int SLOTS_B = 64 * 24 / TPB;   // 6 (TPB=256) or 3 (TPB=512)
  int wm = (w >> 1) * 32, wn = (w & 1) * 32;

  // ---- hoisted addressing (invariant across cj and k0) ----
  int srow_[SLOTS_A], ssoff_[SLOTS_A];
#pragma unroll
  for (int u = 0; u < SLOTS_A; ++u) {
    int p = tid + u * TPB;
    int row = p / 24, sw = p - row * 24;
    int s = (sw & ~7) | ((sw ^ row) & 7);
    srow_[u] = row;
    ssoff_[u] = s * 8;
  }
  int aoff_[6][MF], boff_[6][2];
#pragma unroll
  for (int kk = 0; kk < 6; ++kk) {
    int sbase = kk * 4 + (lane >> 4);
#pragma unroll
    for (int mf = 0; mf < MF; ++mf) {
      int rw = wm + mf * 16 + (lane & 15);
      int sw = (sbase & ~7) | ((sbase ^ rw) & 7);
      aoff_[kk][mf] = rw * 192 + sw * 8;
    }
#pragma unroll
    for (int nf = 0; nf < 2; ++nf) {
      int rw = wn + nf * 16 + (lane & 15);
      int sw = (sbase & ~7) | ((sbase ^ rw) & 7);
      boff_[kk][nf] = rw * 192 + sw * 8;
    }
  }

  for (int cj = 0; cj < cpb; ++cj) {
    int bn = (cg * cpb + cj) * 64;
    if (bn >= N) break;
    f32x4 acc[MF][2] = {};
    for (int k0 = 0; k0 < K; k0 += 192) {
      __syncthreads();
      const ushortT* Abase;
      const ushortT* Bbase;
      int KA, KB;
      if (CHUNK) {
        Abase = (const ushortT*)Ap + (size_t)(k0 / 192) * aStr; KA = 192;
        Bbase = Bw + (size_t)(k0 / 192) * bStr;                 KB = 192;
      } else {
        Abase = (const ushortT*)Ap + (size_t)d * aStr + k0;     KA = K;
        Bbase = Bw + (size_t)d * bStr + k0;                     KB = K;
      }
      if (cj == 0 || K > 192) {
#pragma unroll
        for (int u = 0; u < SLOTS_A; ++u)
          gl16(Abase + (size_t)(bm + srow_[u]) * KA + ssoff_[u], &As[(tid + u * TPB) * 8]);
      }
#pragma unroll
      for (int u = 0; u < SLOTS_B; ++u) {
        int n = bn + srow_[u];   // n>=N reads in-workspace garbage; epilogue discards
        gl16(Bbase + (size_t)n * KB + ssoff_[u], &Bs[(tid + u * TPB) * 8]);
      }
      __syncthreads();
#pragma unroll
      for (int kk = 0; kk < 6; ++kk) {
        bf16x8 a[MF], bfr[2];
#pragma unroll
        for (int mf = 0; mf < MF; ++mf)
          a[mf] = __builtin_bit_cast(bf16x8, *(const short8v*)&As[aoff_[kk][mf]]);
#pragma unroll
        for (int nf = 0; nf < 2; ++nf)
          bfr[nf] = __builtin_bit_cast(bf16x8, *(const short8v*)&Bs[boff_[kk][nf]]);
#pragma unroll
        for (int mf = 0; mf < MF; ++mf)
#pragma unroll
          for (int nf = 0; nf < 2; ++nf)
            acc[mf][nf] = __builtin_amdgcn_mfma_f32_16x16x32_bf16(a[mf], bfr[nf], acc[mf][nf], 0, 0, 0);
      }
    }
#pragma unroll
    for (int mf = 0; mf < MF; ++mf)
#pragma unroll
      for (int nf = 0; nf < 2; ++nf)
#pragma unroll
        for (int j = 0; j < 4; ++j) {
          int rowg = bm + wm + mf * 16 + ((lane >> 4) << 2) + j;
          int colg = bn + wn + nf * 16 + (lane & 15);
          if (colg >= N) continue;
          float vraw = acc[mf][nf][j];
          if (EPI == 0) {
            ((float*)C1)[(size_t)d * c1Str + (size_t)rowg * N + colg] = vraw + (bias ? bias[colg] : 0.f);
          } else if (EPI == 1) {
            ((ushortT*)C1)[(size_t)d * c1Str + (size_t)rowg * N + colg] = f2bf(vraw + (bias ? bias[colg] : 0.f));
          } else if (EPI == 2) {
            if (colg < 192) ((ushortT*)C1)[(size_t)d * c1Str + (size_t)rowg * 192 + colg] = f2bf(vraw);
            else            ((ushortT*)C2)[(size_t)d * c2Str + (size_t)rowg * 192 + colg - 192] = f2bf(vraw);
          } else if (EPI == 3) {
            if (colg < split)
              ((ushortT*)C1)[(size_t)d * c1Str + (size_t)rowg * split + colg] = f2bf(vraw);
            else
              ((ushortT*)C2)[(size_t)d * c2Str + (size_t)rowg * 192 + colg - split] =
                  f2bf(softplusf_(vraw + bias[(size_t)d * 192 + colg - split]));
          } else if (EPI == 5) {
            int dd2 = colg / 384, cc = colg - dd2 * 384;
            if (cc < 192) ((ushortT*)C1)[dd2 * BLC + (size_t)rowg * 192 + cc] = f2bf(vraw);
            else          ((ushortT*)C2)[dd2 * BLC + (size_t)rowg * 192 + cc - 192] = f2bf(vraw);
          } else if (EPI == 6) {
            size_t idx = (size_t)rowg * 192 + colg;
            ((ushortT*)C1)[idx] = f2bf(bf2f(((ushortT*)C1)[idx]) + vraw);
          } else {  // EPI == 7
            ((ushortT*)C1)[(size_t)rowg * 192 + colg] = f2bf(vraw * (0.25f * bias[0]));
          }
        }
  }
}

// ---------------- causal conv K=4 + silu (region, natural layout, gathered taps) ----------------
__global__ void conv_region_k8(const ushortT* __restrict__ xs, const float* __restrict__ wt,
                               const float* __restrict__ cb, ushortT* __restrict__ out, int n8) {
  for (int i = blockIdx.x * blockDim.x + threadIdx.x; i < n8; i += gridDim.x * blockDim.x) {
    int cg = i % 24, row = i / 24;
    int c0 = cg * 8, d = row >> 14, l = row & 4095;
    int base = row - l;
    const float* wtd = wt + d * 768;
    const float* cbd = cb + d * 192;
    float4v b0 = *(const float4v*)(cbd + c0), b1 = *(const float4v*)(cbd + c0 + 4);
    float acc[8] = {b0[0], b0[1], b0[2], b0[3], b1[0], b1[1], b1[2], b1[3]};
#pragma unroll
    for (int k = 0; k < 4; ++k) {
      int lt = l + k - 3;
      if (lt < 0) continue;
      int nr = base + natimg(d, lt);
      short8v v = *(const short8v*)(xs + (size_t)nr * 192 + c0);
      float4v w0 = *(const float4v*)(wtd + k * 192 + c0);
      float4v w1 = *(const float4v*)(wtd + k * 192 + c0 + 4);
#pragma unroll
      for (int j = 0; j < 4; ++j) acc[j]     = fmaf(bf2f((ushortT)v[j]),     w0[j], acc[j]);
#pragma unroll
      for (int j = 0; j < 4; ++j) acc[4 + j] = fmaf(bf2f((ushortT)v[4 + j]), w1[j], acc[4 + j]);
    }
    short8v o;
#pragma unroll
    for (int j = 0; j < 8; ++j) o[j] = (short)f2bf(siluf_(acc[j]));
    *(short8v*)(out + (size_t)(base + natimg(d, l)) * 192 + c0) = o;
  }
}

// ---------------- causal conv K=2 + silu (local, natural layout) ----------------
__global__ void conv_local_k8(const ushortT* __restrict__ xs, const float* __restrict__ wt,
                              const float* __restrict__ cb, ushortT* __restrict__ out, int n8) {
  for (int i = blockIdx.x * blockDim.x + threadIdx.x; i < n8; i += gridDim.x * blockDim.x) {
    int cg = i % 24, m = i / 24;
    int c0 = cg * 8, t = m & 63;
    int nr = natwin(m);
    float4v b0 = *(const float4v*)(cb + c0), b1 = *(const float4v*)(cb + c0 + 4);
    float acc[8] = {b0[0], b0[1], b0[2], b0[3], b1[0], b1[1], b1[2], b1[3]};
    {
      short8v v = *(const short8v*)(xs + (size_t)nr * 192 + c0);
      float4v w0 = *(const float4v*)(wt + 192 + c0);
      float4v w1 = *(const float4v*)(wt + 192 + c0 + 4);
#pragma unroll
      for (int j = 0; j < 4; ++j) acc[j]     = fmaf(bf2f((ushortT)v[j]),     w0[j], acc[j]);
#pragma unroll
      for (int j = 0; j < 4; ++j) acc[4 + j] = fmaf(bf2f((ushortT)v[4 + j]), w1[j], acc[4 + j]);
    }
    if (t > 0) {
      int np = natwin(m - 1);
      short8v v = *(const short8v*)(xs + (size_t)np * 192 + c0);
      float4v w0 = *(const float4v*)(wt + c0);
      float4v w1 = *(const float4v*)(wt + c0 + 4);
#pragma unroll
      for (int j = 0; j < 4; ++j) acc[j]     = fmaf(bf2f((ushortT)v[j]),     w0[j], acc[j]);
#pragma unroll
      for (int j = 0; j < 4; ++j) acc[4 + j] = fmaf(bf2f((ushortT)v[4 + j]), w1[j], acc[4 + j]);
    }
    short8v o;
#pragma unroll
    for (int j = 0; j < 8; ++j) o[j] = (short)f2bf(siluf_(acc[j]));
    *(short8v*)(out + (size_t)nr * 192 + c0) = o;
  }
}

// ======== region scan: 128 chunks x 32 steps, N=16, nat-addressed, bf16 dd+carries ========
__global__ __launch_bounds__(192)
void scanA_r(const ushortT* __restrict__ xc, const ushortT* __restrict__ ddb,
             const ushortT* __restrict__ dtv, const float* __restrict__ Alog,
             ushortT* __restrict__ Pc, ushortT* __restrict__ Hc) {
  __shared__ __align__(16) float dds[32 * 32];
  int blk = blockIdx.x;
  int chunk = blk & 127, seq = blk >> 7, dir = seq >> 2;
  int tid = threadIdx.x, c = tid;
  int seqbase = seq * 4096;
  for (int i = tid; i < 128; i += 192) {
    int t2 = i >> 2, part = i & 3;
    int rr = seqbase + natimg(dir, chunk * 32 + t2);
    short8v v = *(const short8v*)(ddb + (size_t)rr * 32 + part * 8);
    float4v f0, f1;
#pragma unroll
    for (int j = 0; j < 4; ++j) { f0[j] = bf2f((ushortT)v[j]); f1[j] = bf2f((ushortT)v[4 + j]); }
    *(float4v*)&dds[t2 * 32 + part * 8] = f0;
    *(float4v*)&dds[t2 * 32 + part * 8 + 4] = f1;
  }
  float A[16], P[16], H[16];
#pragma unroll
  for (int nn = 0; nn < 16; ++nn) {
    A[nn] = -__expf(Alog[(size_t)(dir * 192 + c) * 16 + nn]);
    P[nn] = 1.f; H[nn] = 0.f;
  }
  __syncthreads();
  for (int t = 0; t < 32; ++t) {
    int nr = seqbase + natimg(dir, chunk * 32 + t);
    float dtvv = bf2f(dtv[(size_t)nr * 192 + c]);
    float xv = bf2f(xc[(size_t)nr * 192 + c]);
    float dx = dtvv * xv;
    const float* dB = dds + t * 32;
#pragma unroll
    for (int nn = 0; nn < 16; ++nn) {
      float a = __expf(dtvv * A[nn]);
      P[nn] *= a;
      H[nn] = fmaf(a, H[nn], dx * dB[nn]);
    }
  }
  size_t ob = ((size_t)(seq * 128 + chunk) * 192 + c) * 16;
  short8v p0, p1, h0, h1;
#pragma unroll
  for (int j = 0; j < 8; ++j) {
    p0[j] = (short)f2bf(P[j]); p1[j] = (short)f2bf(P[8 + j]);
    h0[j] = (short)f2bf(H[j]); h1[j] = (short)f2bf(H[8 + j]);
  }
  *(short8v*)(Pc + ob) = p0; *(short8v*)(Pc + ob + 8) = p1;
  *(short8v*)(Hc + ob) = h0; *(short8v*)(Hc + ob + 8) = h1;
}

__global__ __launch_bounds__(256)
void combine_r(ushortT* __restrict__ Pc, const ushortT* __restrict__ Hc) {
  int gid = blockIdx.x * 256 + threadIdx.x;
  int nn = gid & 15;
  int c = (gid >> 4) % 192;
  int seq = gid / (192 * 16);
  float h = 0.f;
  for (int ch = 0; ch < 128; ++ch) {
    size_t idx = (((size_t)(seq * 128 + ch) * 192 + c) << 4) + nn;
    float nh = fmaf(bf2f(Pc[idx]), h, bf2f(Hc[idx]));
    Pc[idx] = f2bf(h);
    h = nh;
  }
}

__global__ __launch_bounds__(192)
void scanC_r(const ushortT* __restrict__ xc, const ushortT* __restrict__ ddb,
             const ushortT* __restrict__ dtv, ushortT* __restrict__ zg,
             const ushortT* __restrict__ Pc, const float* __restrict__ Alog,
             const float* __restrict__ Dskip) {
  __shared__ __align__(16) float dds[32 * 32];
  int blk = blockIdx.x;
  int chunk = blk & 127, seq = blk >> 7, dir = seq >> 2;
  int tid = threadIdx.x, c = tid;
  int seqbase = seq * 4096;
  for (int i = tid; i < 128; i += 192) {
    int t2 = i >> 2, part = i & 3;
    int rr = seqbase + natimg(dir, chunk * 32 + t2);
    short8v v = *(const short8v*)(ddb + (size_t)rr * 32 + part * 8);
    float4v f0, f1;
#pragma unroll
    for (int j = 0; j < 4; ++j) { f0[j] = bf2f((ushortT)v[j]); f1[j] = bf2f((ushortT)v[4 + j]); }
    *(float4v*)&dds[t2 * 32 + part * 8] = f0;
    *(float4v*)&dds[t2 * 32 + part * 8 + 4] = f1;
  }
  float A[16], h[16];
  size_t ob = ((size_t)(seq * 128 + chunk) * 192 + c) * 16;
#pragma unroll
  for (int nn = 0; nn < 16; ++nn) {
    A[nn] = -__expf(Alog[(size_t)(dir * 192 + c) * 16 + nn]);
    h[nn] = bf2f(Pc[ob + nn]);
  }
  float Dv = Dskip[dir * 192 + c];
  __syncthreads();
  for (int t = 0; t < 32; ++t) {
    int nr = seqbase + natimg(dir, chunk * 32 + t);
    float dtvv = bf2f(dtv[(size_t)nr * 192 + c]);
    float xv = bf2f(xc[(size_t)nr * 192 + c]);
    float dx = dtvv * xv;
    const float* dB = dds + t * 32;
    float y = 0.f;
#pragma unroll
    for (int nn = 0; nn < 16; ++nn) {
      float a = __expf(dtvv * A[nn]);
      h[nn] = fmaf(a, h[nn], dx * dB[nn]);
      y = fmaf(h[nn], dB[16 + nn], y);
    }
    y = fmaf(xv, Dv, y);
    size_t zi = (size_t)nr * 192 + c;
    float zv = bf2f(zg[zi]);
    zg[zi] = f2bf(y * siluf_(zv));
  }
}

// ======== local scan: 256 windows x 4 chunks x 16, N=8, nat-addressed, bf16 dd ========
__global__ __launch_bounds__(192)
void scanA_l(const ushortT* __restrict__ xc, const ushortT* __restrict__ ddb,
             const ushortT* __restrict__ dtv, const float* __restrict__ Alog,
             float* __restrict__ Pc, float* __restrict__ Hc) {
  __shared__ __align__(16) float dds[16 * 16];
  int blk = blockIdx.x;
  int chunk = blk & 3, win = blk >> 2;
  int tid = threadIdx.x, c = tid;
  int m0 = win * 64 + chunk * 16;
  for (int i = tid; i < 32; i += 192) {
    int t2 = i >> 1, part = i & 1;
    int rr = natwin(m0 + t2);
    short8v v = *(const short8v*)(ddb + (size_t)rr * 16 + part * 8);
    float4v f0, f1;
#pragma unroll
    for (int j = 0; j < 4; ++j) { f0[j] = bf2f((ushortT)v[j]); f1[j] = bf2f((ushortT)v[4 + j]); }
    *(float4v*)&dds[t2 * 16 + part * 8] = f0;
    *(float4v*)&dds[t2 * 16 + part * 8 + 4] = f1;
  }
  float A[8], P[8], H[8];
#pragma unroll
  for (int nn = 0; nn < 8; ++nn) {
    A[nn] = -__expf(Alog[(size_t)c * 8 + nn]);
    P[nn] = 1.f; H[nn] = 0.f;
  }
  __syncthreads();
  for (int t = 0; t < 16; ++t) {
    int nr = natwin(m0 + t);
    float dtvv = bf2f(dtv[(size_t)nr * 192 + c]);
    float xv = bf2f(xc[(size_t)nr * 192 + c]);
    float dx = dtvv * xv;
    const float* dB = dds + t * 16;
#pragma unroll
    for (int nn = 0; nn < 8; ++nn) {
      float a = __expf(dtvv * A[nn]);
      P[nn] *= a;
      H[nn] = fmaf(a, H[nn], dx * dB[nn]);
    }
  }
  size_t ob = ((size_t)(win * 4 + chunk) * 192 + c) * 8;
#pragma unroll
  for (int nn = 0; nn < 8; ++nn) { Pc[ob + nn] = P[nn]; Hc[ob + nn] = H[nn]; }
}

__global__ __launch_bounds__(256)
void combine_l(float* __restrict__ Pc, const float* __restrict__ Hc) {
  int gid = blockIdx.x * 256 + threadIdx.x;
  int nn = gid & 7;
  int c = (gid >> 3) % 192;
  int win = gid / (192 * 8);
  float h = 0.f;
#pragma unroll
  for (int ch = 0; ch < 4; ++ch) {
    size_t idx = (((size_t)(win * 4 + ch) * 192 + c) << 3) + nn;
    float nh = fmaf(Pc[idx], h, Hc[idx]);
    Pc[idx] = h;
    h = nh;
  }
}

__global__ __launch_bounds__(192)
void scanC_l(const ushortT* __restrict__ xc, const ushortT* __restrict__ ddb,
             const ushortT* __restrict__ dtv, ushortT* __restrict__ zg,
             const float* __restrict__ Pc, const float* __restrict__ Alog,
             const float* __restrict__ Dskip) {
  __shared__ __align__(16) float dds[16 * 16];
  int blk = blockIdx.x;
  int chunk = blk & 3, win = blk >> 2;
  int tid = threadIdx.x, c = tid;
  int m0 = win * 64 + chunk * 16;
  for (int i = tid; i < 32; i += 192) {
    int t2 = i >> 1, part = i & 1;
    int rr = natwin(m0 + t2);
    short8v v = *(const short8v*)(ddb + (size_t)rr * 16 + part * 8);
    float4v f0, f1;
#pragma unroll
    for (int j = 0; j < 4; ++j) { f0[j] = bf2f((ushortT)v[j]); f1[j] = bf2f((ushortT)v[4 + j]); }
    *(float4v*)&dds[t2 * 16 + part * 8] = f0;
    *(float4v*)&dds[t2 * 16 + part * 8 + 4] = f1;
  }
  float A[8], h[8];
  size_t ob = ((size_t)(win * 4 + chunk) * 192 + c) * 8;
#pragma unroll
  for (int nn = 0; nn < 8; ++nn) {
    A[nn] = -__expf(Alog[(size_t)c * 8 + nn]);
    h[nn] = Pc[ob + nn];
  }
  float Dv = Dskip[c];
  __syncthreads();
  for (int t = 0; t < 16; ++t) {
    int nr = natwin(m0 + t);
    float dtvv = bf2f(dtv[(size_t)nr * 192 + c]);
    float xv = bf2f(xc[(size_t)nr * 192 + c]);
    float dx = dtvv * xv;
    const float* dB = dds + t * 16;
    float y = 0.f;
#pragma unroll
    for (int nn = 0; nn < 8; ++nn) {
      float a = __expf(dtvv * A[nn]);
      h[nn] = fmaf(a, h[nn], dx * dB[nn]);
      y = fmaf(h[nn], dB[8 + nn], y);
    }
    y = fmaf(xv, Dv, y);
    size_t zi = (size_t)nr * 192 + c;
    float zv = bf2f(zg[zi]);
    zg[zi] = f2bf(y * siluf_(zv));
  }
}

// ---------------- depthwise 3x3 + GLU ----------------
__global__ __launch_bounds__(192)
void dwglu_k(const ushortT* __restrict__ h1, const float* __restrict__ dwt,
             const float* __restrict__ dw_b, ushortT* __restrict__ glu) {
  int tid = threadIdx.x;
  int grp = tid % 48, sub = tid / 48;
  int bx = blockIdx.x;
  int b = bx >> 8, xq = (bx >> 4) & 15, ys = bx & 15;
  int x = xq * 4 + sub, y0 = ys * 4;
  int m0 = grp * 8;
  float acc1[4][8], acc2[4][8];
  {
    float4v b1a = *(const float4v*)(dw_b + m0),       b1b = *(const float4v*)(dw_b + m0 + 4);
    float4v b2a = *(const float4v*)(dw_b + 384 + m0), b2b = *(const float4v*)(dw_b + 388 + m0);
#pragma unroll
    for (int iy = 0; iy < 4; ++iy)
#pragma unroll
      for (int j = 0; j < 4; ++j) {
        acc1[iy][j] = b1a[j]; acc1[iy][4 + j] = b1b[j];
        acc2[iy][j] = b2a[j]; acc2[iy][4 + j] = b2b[j];
      }
  }
#pragma unroll
  for (int dy = 0; dy < 3; ++dy) {
#pragma unroll
    for (int dx = 0; dx < 3; ++dx) {
      int xx = x + dx - 1;
      if (xx < 0 || xx >= 64) continue;
      int tap = dy * 3 + dx;
      float4v w1a = *(const float4v*)(dwt + tap * 768 + m0);
      float4v w1b = *(const float4v*)(dwt + tap * 768 + m0 + 4);
      float4v w2a = *(const float4v*)(dwt + tap * 768 + 384 + m0);
      float4v w2b = *(const float4v*)(dwt + tap * 768 + 388 + m0);
#pragma unroll
      for (int iy = 0; iy < 4; ++iy) {
        int yy = y0 + iy + dy - 1;
        if (yy < 0 || yy >= 64) continue;
        size_t pix = (size_t)(b * 4096) + yy * 64 + xx;
        short8v v1 = *(const short8v*)(h1 + pix * 768 + m0);
        short8v v2 = *(const short8v*)(h1 + pix * 768 + 384 + m0);
#pragma unroll
        for (int j = 0; j < 4; ++j) {
          acc1[iy][j]     = fmaf(bf2f((ushortT)v1[j]),     w1a[j], acc1[iy][j]);
          acc1[iy][4 + j] = fmaf(bf2f((ushortT)v1[4 + j]), w1b[j], acc1[iy][4 + j]);
          acc2[iy][j]     = fmaf(bf2f((ushortT)v2[j]),     w2a[j], acc2[iy][j]);
          acc2[iy][4 + j] = fmaf(bf2f((ushortT)v2[4 + j]), w2b[j], acc2[iy][4 + j]);
        }
      }
    }
  }
#pragma unroll
  for (int iy = 0; iy < 4; ++iy) {
    size_t pix = (size_t)(b * 4096) + (y0 + iy) * 64 + x;
    short8v o;
#pragma unroll
    for (int j = 0; j < 8; ++j) o[j] = (short)f2bf(acc1[iy][j] * sigmoidf_(acc2[iy][j]));
    *(short8v*)(glu + pix * 384 + m0) = o;
  }
}

// ---------------- final residual (bf16 fused + fp32 sgout, NHWC->NCHW) ----------------
__global__ __launch_bounds__(256)
void final_k_t(const float* __restrict__ x, const ushortT* __restrict__ fused,
               const float* __restrict__ sgout, const float* __restrict__ gamma,
               float* __restrict__ out) {
  __shared__ float tile[192][65];
  float gm = gamma[0];
  int bb = blockIdx.x >> 6;
  int p0 = (blockIdx.x & 63) << 6;
  int tid = threadIdx.x;
  for (int e = tid; e < 64 * 192; e += 256) {
    int pp = e / 192, c = e % 192;
    size_t idx = ((size_t)(bb * 4096) + p0 + pp) * 192 + c;
    tile[c][pp] = gm * (bf2f(fused[idx]) + sgout[idx]);
  }
  __syncthreads();
  for (int e = tid; e < 192 * 64; e += 256) {
    int c = e / 64, p = e % 64;
    size_t oi = ((size_t)(bb * 192 + c)) * 4096 + p0 + p;
    out[oi] = x[oi] + tile[c][p];
  }
}

extern "C" void kernel_launch(void* const* d_in, const int* in_sizes, int n_in,
                              void* d_out, int out_size, void* d_ws, size_t ws_size,
                              hipStream_t stream) {
  const float* x         = (const float*)d_in[0];
  const float* r_conv_w  = (const float*)d_in[2];
  const float* r_conv_b  = (const float*)d_in[3];
  const float* r_dt_w    = (const float*)d_in[5];
  const float* r_dt_b    = (const float*)d_in[6];
  const float* r_Alog    = (const float*)d_in[7];
  const float* r_D       = (const float*)d_in[8];
  const float* scale_mod = (const float*)d_in[10];
  const float* l_conv_w  = (const float*)d_in[12];
  const float* l_conv_b  = (const float*)d_in[13];
  const float* l_dt_w    = (const float*)d_in[15];
  const float* l_dt_b    = (const float*)d_in[16];
  const float* l_Alog    = (const float*)d_in[17];
  const float* l_D       = (const float*)d_in[18];
  const float* ln_g      = (const float*)d_in[20];
  const float* ln_b      = (const float*)d_in[21];
  const float* c1_b      = (const float*)d_in[23];
  const float* dw_w      = (const float*)d_in[24];
  const float* dw_b      = (const float*)d_in[25];
  const float* c2_b      = (const float*)d_in[27];
  const float* gamma     = (const float*)d_in[28];
  float* out = (float*)d_out;

  float* W = (float*)d_ws;
  const size_t BLC = (size_t)4 * 4096 * 192;
  const size_t OFF_DD  = 5 * BLC + BLC / 2;
  const size_t OFF_DTV = OFF_DD + 2097152;
  const size_t OFF_PC  = OFF_DTV + 6291456;
  const size_t OFF_HC  = OFF_PC + 3145728;
  const size_t OFF_WBF = OFF_HC + 3145728;
  const size_t OFF_WXP = OFF_WBF + 406656;
  const size_t OFF_CWT = OFF_WXP + 105984;

  ushortT* xnbf  = (ushortT*)W;
  ushortT* xcbf  = (ushortT*)(W + BLC);
  ushortT* zbf   = (ushortT*)(W + 3 * BLC);
  ushortT* xsbf  = (ushortT*)(W + 5 * BLC);
  ushortT* ddb   = (ushortT*)(W + OFF_DD);
  ushortT* dtvbf = (ushortT*)(W + OFF_DTV);
  ushortT* Pcb   = (ushortT*)(W + OFF_PC);
  ushortT* Hcb   = (ushortT*)(W + OFF_HC);
  ushortT* xs4   = (ushortT*)(W + OFF_PC);
  float*   Pl    = W + OFF_DTV + 1572864;
  float*   Hl    = W + OFF_DTV + 3145728;
  ushortT* fusedb = (ushortT*)(W + OFF_PC);
  ushortT* h1    = (ushortT*)W;
  ushortT* glu   = (ushortT*)(W + 4 * BLC);
  float*   sgout = W + OFF_HC;
  ushortT* wbf   = (ushortT*)(W + OFF_WBF);
  ushortT* wxpc  = (ushortT*)(W + OFF_WXP);
  float*   cwt   = W + OFF_CWT;

  auto gs = [](size_t n) { size_t g = (n + 255) / 256; return (int)(g > 8192 ? 8192 : g); };
  const int nBLC8 = (int)(BLC / 8);

  // 0. weight prep
  prep_w<<<(813312 + 255) / 256, 256, 0, stream>>>((const float*)d_in[1], (const float*)d_in[4],
                                                   (const float*)d_in[9], (const float*)d_in[11],
                                                   (const float*)d_in[14], (const float*)d_in[19],
                                                   (const float*)d_in[22], (const float*)d_in[26], wbf);
  prep_wxpc<<<828, 256, 0, stream>>>((const float*)d_in[4], r_dt_w,
                                     (const float*)d_in[14], l_dt_w, wxpc);
  prep_cw<<<41, 256, 0, stream>>>(dw_w, r_conv_w, l_conv_w, cwt);
  const float* dwt  = cwt;
  const float* rcwt = cwt + 6912;
  const float* lcwt = cwt + 9984;

  // 1. LayerNorm (bf16 out)
  ln_kernel<<<dim3(256), dim3(256), 0, stream>>>(x, ln_g, ln_b, xnbf);

  // 2. Region branch (natural order)
  const ushortT* w_in  = wbf;
  const ushortT* w_out = wbf + 328704;
  // in-proj: BM=128, 512 threads, grid 512 = 2 blocks/CU, 16 waves/CU
  gemm_mfma<5,128,0,512><<<512, 512, 0, stream>>>(xnbf, w_in, nullptr, xs4, zbf,
                                                  16384, 1536, 192, 4, 6, 512, 0, 0, 0, 0, 0);
  conv_region_k8<<<6144, 256, 0, stream>>>(xs4, rcwt, r_conv_b, xcbf, 4 * nBLC8);
  // xproj+dt: BM=128, 512 threads, grid 1024 = 2 blocks/CU x 2 passes
  gemm_mfma<3,128,0,512><<<1024, 512, 0, stream>>>(xcbf, wxpc, r_dt_b, ddb, dtvbf,
                                                   16384, 224, 192, 2, 2, 256, BLC, 43008,
                                                   524288, 3145728, 32);
  scanA_r<<<2048, 192, 0, stream>>>(xcbf, ddb, dtvbf, r_Alog, Pcb, Hcb);
  combine_r<<<192, 256, 0, stream>>>(Pcb, Hcb);
  scanC_r<<<2048, 192, 0, stream>>>(xcbf, ddb, dtvbf, zbf, Pcb, r_Alog, r_D);
  gemm_mfma<7,64,1,256><<<768, 256, 0, stream>>>(zbf, w_out, scale_mod, fusedb, nullptr,
                                                 16384, 192, 768, 3, 1, 768, BLC, 36864, 0, 0, 0);

  // 3. Local windowed branch
  const ushortT* wl_in  = wbf + 476160;
  const ushortT* wl_out = wbf + 555264;
  const ushortT* wxpc_l = wxpc + 172032;
  gemm_mfma<2,64,0,256><<<512, 256, 0, stream>>>(xnbf, wl_in, nullptr, xsbf, zbf,
                                                 16384, 384, 192, 2, 3, 512, 0, 0, 0, 0, 0);
  conv_local_k8<<<gs(BLC / 8), 256, 0, stream>>>(xsbf, lcwt, l_conv_b, xcbf, nBLC8);
  gemm_mfma<3,64,0,256><<<512, 256, 0, stream>>>(xcbf, wxpc_l, l_dt_b, ddb, dtvbf,
                                                 16384, 208, 192, 2, 2, 512, 0, 0, 0, 0, 16);
  scanA_l<<<1024, 192, 0, stream>>>(xcbf, ddb, dtvbf, l_Alog, Pl, Hl);
  combine_l<<<1536, 256, 0, stream>>>(Pl, Hl);
  scanC_l<<<1024, 192, 0, stream>>>(xcbf, ddb, dtvbf, zbf, Pl, l_Alog, l_D);
  gemm_mfma<6,64,0,256><<<768, 256, 0, stream>>>(zbf, wl_out, nullptr, fusedb, nullptr,
                                                 16384, 192, 192, 3, 1, 768, 0, 0, 0, 0, 0);

  // 4. SGFN + final residual
  const ushortT* w_c1 = wbf + 592128;
  const ushortT* w_c2 = wbf + 739584;
  gemm_mfma<1,64,0,256><<<768, 256, 0, stream>>>(fusedb, w_c1, c1_b, h1, nullptr,
                                                 16384, 768, 192, 3, 4, 768, 0, 0, 0, 0, 0);
  dwglu_k<<<1024, 192, 0, stream>>>(h1, dwt, dw_b, glu);
  gemm_mfma<0,64,0,256><<<768, 256, 0, stream>>>(glu, w_c2, c2_b, sgout, nullptr,
                                                 16384, 192, 384, 3, 1, 768, 0, 0, 0, 0, 0);
  final_k_t<<<256, 256, 0, stream>>>(x, fusedb, sgout, gamma, out);
}

// Round 20
// 389.312 us; speedup vs baseline: 1.0207x; 1.0207x over previous
//
#include <hip/hip_runtime.h>

typedef unsigned short ushortT;
typedef unsigned int uintT;
typedef __bf16 bf16x8 __attribute__((ext_vector_type(8)));
typedef short short8v __attribute__((ext_vector_type(8)));
typedef float f32x4 __attribute__((ext_vector_type(4)));
typedef float float4v __attribute__((ext_vector_type(4)));

#define DEV __device__ __forceinline__

DEV float sigmoidf_(float x) { return 1.f / (1.f + __expf(-x)); }
DEV float siluf_(float x)    { return x * sigmoidf_(x); }
DEV float softplusf_(float x){ return fmaxf(x, 0.f) + log1pf(__expf(-fabsf(x))); }

// native RTNE bf16 convert
DEV ushortT f2bf(float f) {
  __bf16 h = (__bf16)f;
  return __builtin_bit_cast(ushortT, h);
}
DEV float bf2f(ushortT h) {
  union { uintT u; float f; } x; x.u = ((uintT)h) << 16;
  return x.f;
}

// async global->LDS, 16 bytes/lane
typedef const __attribute__((address_space(1))) uintT guintT;
typedef __attribute__((address_space(3))) uintT luintT;
DEV void gl16(const void* g, void* l) {
  __builtin_amdgcn_global_load_lds((guintT*)g, (luintT*)l, 16, 0, 0);
}

// scan-pos -> image-pos within one 4096 sequence
DEV int natimg(int dir, int l) {
  if (dir == 0) return l;
  if (dir == 1) return 4095 - l;
  int s = (dir == 2) ? l : (4095 - l);
  return ((s & 63) << 6) | (s >> 6);
}
// local window scan idx m (0..16383) -> natural row
DEV int natwin(int m) {
  int b = m >> 12, ih = (m >> 9) & 7, iw = (m >> 6) & 7, p = (m >> 3) & 7, q = m & 7;
  return (b << 12) | ((((ih << 3) | p) << 6) | ((iw << 3) | q));
}

// ---------------- LayerNorm over C (NCHW in -> NHWC bf16 out) ----------------
__global__ __launch_bounds__(256)
void ln_kernel(const float* __restrict__ x, const float* __restrict__ g,
               const float* __restrict__ b, ushortT* __restrict__ xn) {
  const int C = 192, HW = 4096;
  __shared__ float tile[64][193];
  __shared__ float red[2][4][64];
  __shared__ float mean_s[64], rstd_s[64];
  int bb = blockIdx.x >> 6;
  int p0 = (blockIdx.x & 63) << 6;
  int tid = threadIdx.x;
  int p = tid & 63, c4 = tid >> 6;
  for (int c = c4; c < C; c += 4)
    tile[p][c] = x[((size_t)(bb * C + c)) * HW + p0 + p];
  __syncthreads();
  float s = 0.f, s2 = 0.f;
  for (int c = c4 * 48; c < c4 * 48 + 48; ++c) { float v = tile[p][c]; s += v; s2 += v * v; }
  red[0][c4][p] = s; red[1][c4][p] = s2;
  __syncthreads();
  if (c4 == 0) {
    float ss = red[0][0][p] + red[0][1][p] + red[0][2][p] + red[0][3][p];
    float qq = red[1][0][p] + red[1][1][p] + red[1][2][p] + red[1][3][p];
    float m = ss * (1.f / 192.f);
    float var = qq * (1.f / 192.f) - m * m;
    mean_s[p] = m;
    rstd_s[p] = rsqrtf(var + 1e-5f);
  }
  __syncthreads();
  for (int e = tid; e < 64 * 192; e += 256) {
    int pp = e / 192, c = e % 192;
    xn[((size_t)bb * HW + p0 + pp) * C + c] =
        f2bf((tile[pp][c] - mean_s[pp]) * rstd_s[pp] * g[c] + b[c]);
  }
}

// ---------------- weight prep (bf16 [N][K]) ----------------
__global__ __launch_bounds__(256)
void prep_w(const float* __restrict__ r_in_w, const float* __restrict__ r_xproj_w,
            const float* __restrict__ r_out_w, const float* __restrict__ l_in_w,
            const float* __restrict__ l_xproj_w, const float* __restrict__ l_out_w,
            const float* __restrict__ c1_w, const float* __restrict__ c2_w,
            ushortT* __restrict__ wbf) {
  int i = blockIdx.x * 256 + threadIdx.x;
  if (i >= 813312) return;
  float v;
  if (i < 294912) {
    int d = i / 73728, j = i % 73728, n = j / 192, k = j % 192;
    v = r_in_w[(size_t)d * 73728 + k * 384 + n];
  } else if (i < 328704) {
    int j = i - 294912; int d = j / 8448, jj = j % 8448, n = jj / 192, k = jj % 192;
    v = r_xproj_w[(size_t)d * 8448 + k * 44 + n];
  } else if (i < 476160) {
    int j = i - 328704; int d = j / 36864, jj = j % 36864, n = jj / 192, k = jj % 192;
    v = r_out_w[(size_t)d * 36864 + k * 192 + n];
  } else if (i < 549888) {
    int j = i - 476160; int n = j / 192, k = j % 192;
    v = l_in_w[k * 384 + n];
  } else if (i < 555264) {
    int j = i - 549888; int n = j / 192, k = j % 192;
    v = l_xproj_w[k * 28 + n];
  } else if (i < 592128) {
    int j = i - 555264; int n = j / 192, k = j % 192;
    v = l_out_w[k * 192 + n];
  } else if (i < 739584) {
    v = c1_w[i - 592128];
  } else {
    v = c2_w[i - 739584];
  }
  wbf[i] = f2bf(v);
}

// ---------------- fused xproj(B,C)+dt weights ----------------
__global__ __launch_bounds__(256)
void prep_wxpc(const float* __restrict__ r_xproj_w, const float* __restrict__ r_dt_w,
               const float* __restrict__ l_xproj_w, const float* __restrict__ l_dt_w,
               ushortT* __restrict__ wxpc) {
  int i = blockIdx.x * 256 + threadIdx.x;
  if (i >= 211968) return;
  float v;
  if (i < 172032) {
    int d = i / 43008, j = i % 43008, n = j / 192, k = j % 192;
    if (n < 32) v = r_xproj_w[(size_t)d * 8448 + k * 44 + 12 + n];
    else {
      int np = n - 32;
      v = 0.f;
#pragma unroll
      for (int r = 0; r < 12; ++r)
        v += r_xproj_w[(size_t)d * 8448 + k * 44 + r] * r_dt_w[(size_t)d * 2304 + r * 192 + np];
    }
  } else {
    int j = i - 172032, n = j / 192, k = j % 192;
    if (n < 16) v = l_xproj_w[k * 28 + 12 + n];
    else {
      int np = n - 16;
      v = 0.f;
#pragma unroll
      for (int r = 0; r < 12; ++r)
        v += l_xproj_w[k * 28 + r] * l_dt_w[r * 192 + np];
    }
  }
  wxpc[i] = f2bf(v);
}

// ---------------- conv/dw weight transposes ----------------
__global__ __launch_bounds__(256)
void prep_cw(const float* __restrict__ dw_w, const float* __restrict__ r_conv_w,
             const float* __restrict__ l_conv_w, float* __restrict__ cwt) {
  int i = blockIdx.x * 256 + threadIdx.x;
  if (i < 6912) {
    int ch = i / 9, tap = i % 9;
    cwt[tap * 768 + ch] = dw_w[i];
  } else if (i < 6912 + 3072) {
    int j = i - 6912; int d = j / 768, ch = (j % 768) / 4, k = j & 3;
    cwt[6912 + (d * 4 + k) * 192 + ch] = r_conv_w[j];
  } else if (i < 6912 + 3072 + 384) {
    int j = i - 6912 - 3072; int ch = j >> 1, k = j & 1;
    cwt[9984 + k * 192 + ch] = l_conv_w[j];
  }
}

// ---------------- MFMA bf16 GEMM (natural A, gload_lds, hoisted addressing) ----------------
// EPI 0 fp32+bias; 1 bf16+bias; 2 split N=384; 3 xproj+dt (split, dd bf16);
// 5 split 4-dir N=1536; 6 bf16 accumulate; 7 bf16 scaled (0.25*bias[0]).
// CHUNK=1: A,B chunk-major over 192-wide K chunks.
// TPB: threads/block (256 -> BM=64, 4 waves; 512 -> BM=128, 8 waves). MF=2 always.
template <int EPI, int BM, int CHUNK, int TPB>
__global__ __launch_bounds__(TPB)
void gemm_mfma(const void* __restrict__ Ap, const ushortT* __restrict__ Bw,
               const float* __restrict__ bias, void* __restrict__ C1,
               void* __restrict__ C2, int M, int N, int K, int nGc, int cpb,
               int tilesPerDir, size_t aStr, size_t bStr, size_t c1Str, size_t c2Str,
               int split) {
  const size_t BLC = (size_t)4 * 4096 * 192;
  __shared__ __align__(16) ushortT As[BM * 192];
  __shared__ __align__(16) ushortT Bs[64 * 192];
  int nwg = gridDim.x;
  int bid = blockIdx.x;
  int q = nwg >> 3, r = nwg & 7, xq = bid & 7, o = bid >> 3;
  int wg = (xq < r ? xq * (q + 1) : r * (q + 1) + (xq - r) * q) + o;
  int d = wg / tilesPerDir;
  wg -= d * tilesPerDir;
  int rt = wg / nGc, cg = wg % nGc;
  int bm = rt * BM;
  int tid = threadIdx.x;
  int lane = tid & 63, w = tid >> 6;
  constexpr int MF = 2;
  constexpr int SLOTS_A = BM * 24 / TPB;   // 6
  constexpr int SLOTS_B = 64 * 24 / TPB;   // 6 (TPB=256) or 3 (TPB=512)
  int wm = (w >> 1) * 32, wn = (w & 1) * 32;

  // ---- hoisted addressing (invariant across cj and k0) ----
  int srow_[SLOTS_A], ssoff_[SLOTS_A];
#pragma unroll
  for (int u = 0; u < SLOTS_A; ++u) {
    int p = tid + u * TPB;
    int row = p / 24, sw = p - row * 24;
    int s = (sw & ~7) | ((sw ^ row) & 7);
    srow_[u] = row;
    ssoff_[u] = s * 8;
  }
  int aoff_[6][MF], boff_[6][2];
#pragma unroll
  for (int kk = 0; kk < 6; ++kk) {
    int sbase = kk * 4 + (lane >> 4);
#pragma unroll
    for (int mf = 0; mf < MF; ++mf) {
      int rw = wm + mf * 16 + (lane & 15);
      int sw = (sbase & ~7) | ((sbase ^ rw) & 7);
      aoff_[kk][mf] = rw * 192 + sw * 8;
    }
#pragma unroll
    for (int nf = 0; nf < 2; ++nf) {
      int rw = wn + nf * 16 + (lane & 15);
      int sw = (sbase & ~7) | ((sbase ^ rw) & 7);
      boff_[kk][nf] = rw * 192 + sw * 8;
    }
  }

  for (int cj = 0; cj < cpb; ++cj) {
    int bn = (cg * cpb + cj) * 64;
    if (bn >= N) break;
    f32x4 acc[MF][2] = {};
    for (int k0 = 0; k0 < K; k0 += 192) {
      __syncthreads();
      const ushortT* Abase;
      const ushortT* Bbase;
      int KA, KB;
      if (CHUNK) {
        Abase = (const ushortT*)Ap + (size_t)(k0 / 192) * aStr; KA = 192;
        Bbase = Bw + (size_t)(k0 / 192) * bStr;                 KB = 192;
      } else {
        Abase = (const ushortT*)Ap + (size_t)d * aStr + k0;     KA = K;
        Bbase = Bw + (size_t)d * bStr + k0;                     KB = K;
      }
      if (cj == 0 || K > 192) {
#pragma unroll
        for (int u = 0; u < SLOTS_A; ++u)
          gl16(Abase + (size_t)(bm + srow_[u]) * KA + ssoff_[u], &As[(tid + u * TPB) * 8]);
      }
#pragma unroll
      for (int u = 0; u < SLOTS_B; ++u) {
        int n = bn + srow_[u];   // n>=N reads in-workspace garbage; epilogue discards
        gl16(Bbase + (size_t)n * KB + ssoff_[u], &Bs[(tid + u * TPB) * 8]);
      }
      __syncthreads();
#pragma unroll
      for (int kk = 0; kk < 6; ++kk) {
        bf16x8 a[MF], bfr[2];
#pragma unroll
        for (int mf = 0; mf < MF; ++mf)
          a[mf] = __builtin_bit_cast(bf16x8, *(const short8v*)&As[aoff_[kk][mf]]);
#pragma unroll
        for (int nf = 0; nf < 2; ++nf)
          bfr[nf] = __builtin_bit_cast(bf16x8, *(const short8v*)&Bs[boff_[kk][nf]]);
#pragma unroll
        for (int mf = 0; mf < MF; ++mf)
#pragma unroll
          for (int nf = 0; nf < 2; ++nf)
            acc[mf][nf] = __builtin_amdgcn_mfma_f32_16x16x32_bf16(a[mf], bfr[nf], acc[mf][nf], 0, 0, 0);
      }
    }
#pragma unroll
    for (int mf = 0; mf < MF; ++mf)
#pragma unroll
      for (int nf = 0; nf < 2; ++nf)
#pragma unroll
        for (int j = 0; j < 4; ++j) {
          int rowg = bm + wm + mf * 16 + ((lane >> 4) << 2) + j;
          int colg = bn + wn + nf * 16 + (lane & 15);
          if (colg >= N) continue;
          float vraw = acc[mf][nf][j];
          if (EPI == 0) {
            ((float*)C1)[(size_t)d * c1Str + (size_t)rowg * N + colg] = vraw + (bias ? bias[colg] : 0.f);
          } else if (EPI == 1) {
            ((ushortT*)C1)[(size_t)d * c1Str + (size_t)rowg * N + colg] = f2bf(vraw + (bias ? bias[colg] : 0.f));
          } else if (EPI == 2) {
            if (colg < 192) ((ushortT*)C1)[(size_t)d * c1Str + (size_t)rowg * 192 + colg] = f2bf(vraw);
            else            ((ushortT*)C2)[(size_t)d * c2Str + (size_t)rowg * 192 + colg - 192] = f2bf(vraw);
          } else if (EPI == 3) {
            if (colg < split)
              ((ushortT*)C1)[(size_t)d * c1Str + (size_t)rowg * split + colg] = f2bf(vraw);
            else
              ((ushortT*)C2)[(size_t)d * c2Str + (size_t)rowg * 192 + colg - split] =
                  f2bf(softplusf_(vraw + bias[(size_t)d * 192 + colg - split]));
          } else if (EPI == 5) {
            int dd2 = colg / 384, cc = colg - dd2 * 384;
            if (cc < 192) ((ushortT*)C1)[dd2 * BLC + (size_t)rowg * 192 + cc] = f2bf(vraw);
            else          ((ushortT*)C2)[dd2 * BLC + (size_t)rowg * 192 + cc - 192] = f2bf(vraw);
          } else if (EPI == 6) {
            size_t idx = (size_t)rowg * 192 + colg;
            ((ushortT*)C1)[idx] = f2bf(bf2f(((ushortT*)C1)[idx]) + vraw);
          } else {  // EPI == 7
            ((ushortT*)C1)[(size_t)rowg * 192 + colg] = f2bf(vraw * (0.25f * bias[0]));
          }
        }
  }
}

// ---------------- causal conv K=4 + silu (region, natural layout, gathered taps) ----------------
__global__ void conv_region_k8(const ushortT* __restrict__ xs, const float* __restrict__ wt,
                               const float* __restrict__ cb, ushortT* __restrict__ out, int n8) {
  for (int i = blockIdx.x * blockDim.x + threadIdx.x; i < n8; i += gridDim.x * blockDim.x) {
    int cg = i % 24, row = i / 24;
    int c0 = cg * 8, d = row >> 14, l = row & 4095;
    int base = row - l;
    const float* wtd = wt + d * 768;
    const float* cbd = cb + d * 192;
    float4v b0 = *(const float4v*)(cbd + c0), b1 = *(const float4v*)(cbd + c0 + 4);
    float acc[8] = {b0[0], b0[1], b0[2], b0[3], b1[0], b1[1], b1[2], b1[3]};
#pragma unroll
    for (int k = 0; k < 4; ++k) {
      int lt = l + k - 3;
      if (lt < 0) continue;
      int nr = base + natimg(d, lt);
      short8v v = *(const short8v*)(xs + (size_t)nr * 192 + c0);
      float4v w0 = *(const float4v*)(wtd + k * 192 + c0);
      float4v w1 = *(const float4v*)(wtd + k * 192 + c0 + 4);
#pragma unroll
      for (int j = 0; j < 4; ++j) acc[j]     = fmaf(bf2f((ushortT)v[j]),     w0[j], acc[j]);
#pragma unroll
      for (int j = 0; j < 4; ++j) acc[4 + j] = fmaf(bf2f((ushortT)v[4 + j]), w1[j], acc[4 + j]);
    }
    short8v o;
#pragma unroll
    for (int j = 0; j < 8; ++j) o[j] = (short)f2bf(siluf_(acc[j]));
    *(short8v*)(out + (size_t)(base + natimg(d, l)) * 192 + c0) = o;
  }
}

// ---------------- causal conv K=2 + silu (local, natural layout) ----------------
__global__ void conv_local_k8(const ushortT* __restrict__ xs, const float* __restrict__ wt,
                              const float* __restrict__ cb, ushortT* __restrict__ out, int n8) {
  for (int i = blockIdx.x * blockDim.x + threadIdx.x; i < n8; i += gridDim.x * blockDim.x) {
    int cg = i % 24, m = i / 24;
    int c0 = cg * 8, t = m & 63;
    int nr = natwin(m);
    float4v b0 = *(const float4v*)(cb + c0), b1 = *(const float4v*)(cb + c0 + 4);
    float acc[8] = {b0[0], b0[1], b0[2], b0[3], b1[0], b1[1], b1[2], b1[3]};
    {
      short8v v = *(const short8v*)(xs + (size_t)nr * 192 + c0);
      float4v w0 = *(const float4v*)(wt + 192 + c0);
      float4v w1 = *(const float4v*)(wt + 192 + c0 + 4);
#pragma unroll
      for (int j = 0; j < 4; ++j) acc[j]     = fmaf(bf2f((ushortT)v[j]),     w0[j], acc[j]);
#pragma unroll
      for (int j = 0; j < 4; ++j) acc[4 + j] = fmaf(bf2f((ushortT)v[4 + j]), w1[j], acc[4 + j]);
    }
    if (t > 0) {
      int np = natwin(m - 1);
      short8v v = *(const short8v*)(xs + (size_t)np * 192 + c0);
      float4v w0 = *(const float4v*)(wt + c0);
      float4v w1 = *(const float4v*)(wt + c0 + 4);
#pragma unroll
      for (int j = 0; j < 4; ++j) acc[j]     = fmaf(bf2f((ushortT)v[j]),     w0[j], acc[j]);
#pragma unroll
      for (int j = 0; j < 4; ++j) acc[4 + j] = fmaf(bf2f((ushortT)v[4 + j]), w1[j], acc[4 + j]);
    }
    short8v o;
#pragma unroll
    for (int j = 0; j < 8; ++j) o[j] = (short)f2bf(siluf_(acc[j]));
    *(short8v*)(out + (size_t)nr * 192 + c0) = o;
  }
}

// ======== region scan: 128 chunks x 32 steps, N=16, nat-addressed, bf16 dd+carries ========
__global__ __launch_bounds__(192)
void scanA_r(const ushortT* __restrict__ xc, const ushortT* __restrict__ ddb,
             const ushortT* __restrict__ dtv, const float* __restrict__ Alog,
             ushortT* __restrict__ Pc, ushortT* __restrict__ Hc) {
  __shared__ __align__(16) float dds[32 * 32];
  int blk = blockIdx.x;
  int chunk = blk & 127, seq = blk >> 7, dir = seq >> 2;
  int tid = threadIdx.x, c = tid;
  int seqbase = seq * 4096;
  for (int i = tid; i < 128; i += 192) {
    int t2 = i >> 2, part = i & 3;
    int rr = seqbase + natimg(dir, chunk * 32 + t2);
    short8v v = *(const short8v*)(ddb + (size_t)rr * 32 + part * 8);
    float4v f0, f1;
#pragma unroll
    for (int j = 0; j < 4; ++j) { f0[j] = bf2f((ushortT)v[j]); f1[j] = bf2f((ushortT)v[4 + j]); }
    *(float4v*)&dds[t2 * 32 + part * 8] = f0;
    *(float4v*)&dds[t2 * 32 + part * 8 + 4] = f1;
  }
  float A[16], P[16], H[16];
#pragma unroll
  for (int nn = 0; nn < 16; ++nn) {
    A[nn] = -__expf(Alog[(size_t)(dir * 192 + c) * 16 + nn]);
    P[nn] = 1.f; H[nn] = 0.f;
  }
  __syncthreads();
  for (int t = 0; t < 32; ++t) {
    int nr = seqbase + natimg(dir, chunk * 32 + t);
    float dtvv = bf2f(dtv[(size_t)nr * 192 + c]);
    float xv = bf2f(xc[(size_t)nr * 192 + c]);
    float dx = dtvv * xv;
    const float* dB = dds + t * 32;
#pragma unroll
    for (int nn = 0; nn < 16; ++nn) {
      float a = __expf(dtvv * A[nn]);
      P[nn] *= a;
      H[nn] = fmaf(a, H[nn], dx * dB[nn]);
    }
  }
  size_t ob = ((size_t)(seq * 128 + chunk) * 192 + c) * 16;
  short8v p0, p1, h0, h1;
#pragma unroll
  for (int j = 0; j < 8; ++j) {
    p0[j] = (short)f2bf(P[j]); p1[j] = (short)f2bf(P[8 + j]);
    h0[j] = (short)f2bf(H[j]); h1[j] = (short)f2bf(H[8 + j]);
  }
  *(short8v*)(Pc + ob) = p0; *(short8v*)(Pc + ob + 8) = p1;
  *(short8v*)(Hc + ob) = h0; *(short8v*)(Hc + ob + 8) = h1;
}

__global__ __launch_bounds__(256)
void combine_r(ushortT* __restrict__ Pc, const ushortT* __restrict__ Hc) {
  int gid = blockIdx.x * 256 + threadIdx.x;
  int nn = gid & 15;
  int c = (gid >> 4) % 192;
  int seq = gid / (192 * 16);
  float h = 0.f;
  for (int ch = 0; ch < 128; ++ch) {
    size_t idx = (((size_t)(seq * 128 + ch) * 192 + c) << 4) + nn;
    float nh = fmaf(bf2f(Pc[idx]), h, bf2f(Hc[idx]));
    Pc[idx] = f2bf(h);
    h = nh;
  }
}

__global__ __launch_bounds__(192)
void scanC_r(const ushortT* __restrict__ xc, const ushortT* __restrict__ ddb,
             const ushortT* __restrict__ dtv, ushortT* __restrict__ zg,
             const ushortT* __restrict__ Pc, const float* __restrict__ Alog,
             const float* __restrict__ Dskip) {
  __shared__ __align__(16) float dds[32 * 32];
  int blk = blockIdx.x;
  int chunk = blk & 127, seq = blk >> 7, dir = seq >> 2;
  int tid = threadIdx.x, c = tid;
  int seqbase = seq * 4096;
  for (int i = tid; i < 128; i += 192) {
    int t2 = i >> 2, part = i & 3;
    int rr = seqbase + natimg(dir, chunk * 32 + t2);
    short8v v = *(const short8v*)(ddb + (size_t)rr * 32 + part * 8);
    float4v f0, f1;
#pragma unroll
    for (int j = 0; j < 4; ++j) { f0[j] = bf2f((ushortT)v[j]); f1[j] = bf2f((ushortT)v[4 + j]); }
    *(float4v*)&dds[t2 * 32 + part * 8] = f0;
    *(float4v*)&dds[t2 * 32 + part * 8 + 4] = f1;
  }
  float A[16], h[16];
  size_t ob = ((size_t)(seq * 128 + chunk) * 192 + c) * 16;
#pragma unroll
  for (int nn = 0; nn < 16; ++nn) {
    A[nn] = -__expf(Alog[(size_t)(dir * 192 + c) * 16 + nn]);
    h[nn] = bf2f(Pc[ob + nn]);
  }
  float Dv = Dskip[dir * 192 + c];
  __syncthreads();
  for (int t = 0; t < 32; ++t) {
    int nr = seqbase + natimg(dir, chunk * 32 + t);
    float dtvv = bf2f(dtv[(size_t)nr * 192 + c]);
    float xv = bf2f(xc[(size_t)nr * 192 + c]);
    float dx = dtvv * xv;
    const float* dB = dds + t * 32;
    float y = 0.f;
#pragma unroll
    for (int nn = 0; nn < 16; ++nn) {
      float a = __expf(dtvv * A[nn]);
      h[nn] = fmaf(a, h[nn], dx * dB[nn]);
      y = fmaf(h[nn], dB[16 + nn], y);
    }
    y = fmaf(xv, Dv, y);
    size_t zi = (size_t)nr * 192 + c;
    float zv = bf2f(zg[zi]);
    zg[zi] = f2bf(y * siluf_(zv));
  }
}

// ======== local scan: 256 windows x 4 chunks x 16, N=8, nat-addressed, bf16 dd ========
__global__ __launch_bounds__(192)
void scanA_l(const ushortT* __restrict__ xc, const ushortT* __restrict__ ddb,
             const ushortT* __restrict__ dtv, const float* __restrict__ Alog,
             float* __restrict__ Pc, float* __restrict__ Hc) {
  __shared__ __align__(16) float dds[16 * 16];
  int blk = blockIdx.x;
  int chunk = blk & 3, win = blk >> 2;
  int tid = threadIdx.x, c = tid;
  int m0 = win * 64 + chunk * 16;
  for (int i = tid; i < 32; i += 192) {
    int t2 = i >> 1, part = i & 1;
    int rr = natwin(m0 + t2);
    short8v v = *(const short8v*)(ddb + (size_t)rr * 16 + part * 8);
    float4v f0, f1;
#pragma unroll
    for (int j = 0; j < 4; ++j) { f0[j] = bf2f((ushortT)v[j]); f1[j] = bf2f((ushortT)v[4 + j]); }
    *(float4v*)&dds[t2 * 16 + part * 8] = f0;
    *(float4v*)&dds[t2 * 16 + part * 8 + 4] = f1;
  }
  float A[8], P[8], H[8];
#pragma unroll
  for (int nn = 0; nn < 8; ++nn) {
    A[nn] = -__expf(Alog[(size_t)c * 8 + nn]);
    P[nn] = 1.f; H[nn] = 0.f;
  }
  __syncthreads();
  for (int t = 0; t < 16; ++t) {
    int nr = natwin(m0 + t);
    float dtvv = bf2f(dtv[(size_t)nr * 192 + c]);
    float xv = bf2f(xc[(size_t)nr * 192 + c]);
    float dx = dtvv * xv;
    const float* dB = dds + t * 16;
#pragma unroll
    for (int nn = 0; nn < 8; ++nn) {
      float a = __expf(dtvv * A[nn]);
      P[nn] *= a;
      H[nn] = fmaf(a, H[nn], dx * dB[nn]);
    }
  }
  size_t ob = ((size_t)(win * 4 + chunk) * 192 + c) * 8;
#pragma unroll
  for (int nn = 0; nn < 8; ++nn) { Pc[ob + nn] = P[nn]; Hc[ob + nn] = H[nn]; }
}

__global__ __launch_bounds__(256)
void combine_l(float* __restrict__ Pc, const float* __restrict__ Hc) {
  int gid = blockIdx.x * 256 + threadIdx.x;
  int nn = gid & 7;
  int c = (gid >> 3) % 192;
  int win = gid / (192 * 8);
  float h = 0.f;
#pragma unroll
  for (int ch = 0; ch < 4; ++ch) {
    size_t idx = (((size_t)(win * 4 + ch) * 192 + c) << 3) + nn;
    float nh = fmaf(Pc[idx], h, Hc[idx]);
    Pc[idx] = h;
    h = nh;
  }
}

__global__ __launch_bounds__(192)
void scanC_l(const ushortT* __restrict__ xc, const ushortT* __restrict__ ddb,
             const ushortT* __restrict__ dtv, ushortT* __restrict__ zg,
             const float* __restrict__ Pc, const float* __restrict__ Alog,
             const float* __restrict__ Dskip) {
  __shared__ __align__(16) float dds[16 * 16];
  int blk = blockIdx.x;
  int chunk = blk & 3, win = blk >> 2;
  int tid = threadIdx.x, c = tid;
  int m0 = win * 64 + chunk * 16;
  for (int i = tid; i < 32; i += 192) {
    int t2 = i >> 1, part = i & 1;
    int rr = natwin(m0 + t2);
    short8v v = *(const short8v*)(ddb + (size_t)rr * 16 + part * 8);
    float4v f0, f1;
#pragma unroll
    for (int j = 0; j < 4; ++j) { f0[j] = bf2f((ushortT)v[j]); f1[j] = bf2f((ushortT)v[4 + j]); }
    *(float4v*)&dds[t2 * 16 + part * 8] = f0;
    *(float4v*)&dds[t2 * 16 + part * 8 + 4] = f1;
  }
  float A[8], h[8];
  size_t ob = ((size_t)(win * 4 + chunk) * 192 + c) * 8;
#pragma unroll
  for (int nn = 0; nn < 8; ++nn) {
    A[nn] = -__expf(Alog[(size_t)c * 8 + nn]);
    h[nn] = Pc[ob + nn];
  }
  float Dv = Dskip[c];
  __syncthreads();
  for (int t = 0; t < 16; ++t) {
    int nr = natwin(m0 + t);
    float dtvv = bf2f(dtv[(size_t)nr * 192 + c]);
    float xv = bf2f(xc[(size_t)nr * 192 + c]);
    float dx = dtvv * xv;
    const float* dB = dds + t * 16;
    float y = 0.f;
#pragma unroll
    for (int nn = 0; nn < 8; ++nn) {
      float a = __expf(dtvv * A[nn]);
      h[nn] = fmaf(a, h[nn], dx * dB[nn]);
      y = fmaf(h[nn], dB[8 + nn], y);
    }
    y = fmaf(xv, Dv, y);
    size_t zi = (size_t)nr * 192 + c;
    float zv = bf2f(zg[zi]);
    zg[zi] = f2bf(y * siluf_(zv));
  }
}

// ---------------- depthwise 3x3 + GLU ----------------
__global__ __launch_bounds__(192)
void dwglu_k(const ushortT* __restrict__ h1, const float* __restrict__ dwt,
             const float* __restrict__ dw_b, ushortT* __restrict__ glu) {
  int tid = threadIdx.x;
  int grp = tid % 48, sub = tid / 48;
  int bx = blockIdx.x;
  int b = bx >> 8, xq = (bx >> 4) & 15, ys = bx & 15;
  int x = xq * 4 + sub, y0 = ys * 4;
  int m0 = grp * 8;
  float acc1[4][8], acc2[4][8];
  {
    float4v b1a = *(const float4v*)(dw_b + m0),       b1b = *(const float4v*)(dw_b + m0 + 4);
    float4v b2a = *(const float4v*)(dw_b + 384 + m0), b2b = *(const float4v*)(dw_b + 388 + m0);
#pragma unroll
    for (int iy = 0; iy < 4; ++iy)
#pragma unroll
      for (int j = 0; j < 4; ++j) {
        acc1[iy][j] = b1a[j]; acc1[iy][4 + j] = b1b[j];
        acc2[iy][j] = b2a[j]; acc2[iy][4 + j] = b2b[j];
      }
  }
#pragma unroll
  for (int dy = 0; dy < 3; ++dy) {
#pragma unroll
    for (int dx = 0; dx < 3; ++dx) {
      int xx = x + dx - 1;
      if (xx < 0 || xx >= 64) continue;
      int tap = dy * 3 + dx;
      float4v w1a = *(const float4v*)(dwt + tap * 768 + m0);
      float4v w1b = *(const float4v*)(dwt + tap * 768 + m0 + 4);
      float4v w2a = *(const float4v*)(dwt + tap * 768 + 384 + m0);
      float4v w2b = *(const float4v*)(dwt + tap * 768 + 388 + m0);
#pragma unroll
      for (int iy = 0; iy < 4; ++iy) {
        int yy = y0 + iy + dy - 1;
        if (yy < 0 || yy >= 64) continue;
        size_t pix = (size_t)(b * 4096) + yy * 64 + xx;
        short8v v1 = *(const short8v*)(h1 + pix * 768 + m0);
        short8v v2 = *(const short8v*)(h1 + pix * 768 + 384 + m0);
#pragma unroll
        for (int j = 0; j < 4; ++j) {
          acc1[iy][j]     = fmaf(bf2f((ushortT)v1[j]),     w1a[j], acc1[iy][j]);
          acc1[iy][4 + j] = fmaf(bf2f((ushortT)v1[4 + j]), w1b[j], acc1[iy][4 + j]);
          acc2[iy][j]     = fmaf(bf2f((ushortT)v2[j]),     w2a[j], acc2[iy][j]);
          acc2[iy][4 + j] = fmaf(bf2f((ushortT)v2[4 + j]), w2b[j], acc2[iy][4 + j]);
        }
      }
    }
  }
#pragma unroll
  for (int iy = 0; iy < 4; ++iy) {
    size_t pix = (size_t)(b * 4096) + (y0 + iy) * 64 + x;
    short8v o;
#pragma unroll
    for (int j = 0; j < 8; ++j) o[j] = (short)f2bf(acc1[iy][j] * sigmoidf_(acc2[iy][j]));
    *(short8v*)(glu + pix * 384 + m0) = o;
  }
}

// ---------------- final residual (bf16 fused + fp32 sgout, NHWC->NCHW) ----------------
__global__ __launch_bounds__(256)
void final_k_t(const float* __restrict__ x, const ushortT* __restrict__ fused,
               const float* __restrict__ sgout, const float* __restrict__ gamma,
               float* __restrict__ out) {
  __shared__ float tile[192][65];
  float gm = gamma[0];
  int bb = blockIdx.x >> 6;
  int p0 = (blockIdx.x & 63) << 6;
  int tid = threadIdx.x;
  for (int e = tid; e < 64 * 192; e += 256) {
    int pp = e / 192, c = e % 192;
    size_t idx = ((size_t)(bb * 4096) + p0 + pp) * 192 + c;
    tile[c][pp] = gm * (bf2f(fused[idx]) + sgout[idx]);
  }
  __syncthreads();
  for (int e = tid; e < 192 * 64; e += 256) {
    int c = e / 64, p = e % 64;
    size_t oi = ((size_t)(bb * 192 + c)) * 4096 + p0 + p;
    out[oi] = x[oi] + tile[c][p];
  }
}

extern "C" void kernel_launch(void* const* d_in, const int* in_sizes, int n_in,
                              void* d_out, int out_size, void* d_ws, size_t ws_size,
                              hipStream_t stream) {
  const float* x         = (const float*)d_in[0];
  const float* r_conv_w  = (const float*)d_in[2];
  const float* r_conv_b  = (const float*)d_in[3];
  const float* r_dt_w    = (const float*)d_in[5];
  const float* r_dt_b    = (const float*)d_in[6];
  const float* r_Alog    = (const float*)d_in[7];
  const float* r_D       = (const float*)d_in[8];
  const float* scale_mod = (const float*)d_in[10];
  const float* l_conv_w  = (const float*)d_in[12];
  const float* l_conv_b  = (const float*)d_in[13];
  const float* l_dt_w    = (const float*)d_in[15];
  const float* l_dt_b    = (const float*)d_in[16];
  const float* l_Alog    = (const float*)d_in[17];
  const float* l_D       = (const float*)d_in[18];
  const float* ln_g      = (const float*)d_in[20];
  const float* ln_b      = (const float*)d_in[21];
  const float* c1_b      = (const float*)d_in[23];
  const float* dw_w      = (const float*)d_in[24];
  const float* dw_b      = (const float*)d_in[25];
  const float* c2_b      = (const float*)d_in[27];
  const float* gamma     = (const float*)d_in[28];
  float* out = (float*)d_out;

  float* W = (float*)d_ws;
  const size_t BLC = (size_t)4 * 4096 * 192;
  const size_t OFF_DD  = 5 * BLC + BLC / 2;
  const size_t OFF_DTV = OFF_DD + 2097152;
  const size_t OFF_PC  = OFF_DTV + 6291456;
  const size_t OFF_HC  = OFF_PC + 3145728;
  const size_t OFF_WBF = OFF_HC + 3145728;
  const size_t OFF_WXP = OFF_WBF + 406656;
  const size_t OFF_CWT = OFF_WXP + 105984;

  ushortT* xnbf  = (ushortT*)W;
  ushortT* xcbf  = (ushortT*)(W + BLC);
  ushortT* zbf   = (ushortT*)(W + 3 * BLC);
  ushortT* xsbf  = (ushortT*)(W + 5 * BLC);
  ushortT* ddb   = (ushortT*)(W + OFF_DD);
  ushortT* dtvbf = (ushortT*)(W + OFF_DTV);
  ushortT* Pcb   = (ushortT*)(W + OFF_PC);
  ushortT* Hcb   = (ushortT*)(W + OFF_HC);
  ushortT* xs4   = (ushortT*)(W + OFF_PC);
  float*   Pl    = W + OFF_DTV + 1572864;
  float*   Hl    = W + OFF_DTV + 3145728;
  ushortT* fusedb = (ushortT*)(W + OFF_PC);
  ushortT* h1    = (ushortT*)W;
  ushortT* glu   = (ushortT*)(W + 4 * BLC);
  float*   sgout = W + OFF_HC;
  ushortT* wbf   = (ushortT*)(W + OFF_WBF);
  ushortT* wxpc  = (ushortT*)(W + OFF_WXP);
  float*   cwt   = W + OFF_CWT;

  auto gs = [](size_t n) { size_t g = (n + 255) / 256; return (int)(g > 8192 ? 8192 : g); };
  const int nBLC8 = (int)(BLC / 8);

  // 0. weight prep
  prep_w<<<(813312 + 255) / 256, 256, 0, stream>>>((const float*)d_in[1], (const float*)d_in[4],
                                                   (const float*)d_in[9], (const float*)d_in[11],
                                                   (const float*)d_in[14], (const float*)d_in[19],
                                                   (const float*)d_in[22], (const float*)d_in[26], wbf);
  prep_wxpc<<<828, 256, 0, stream>>>((const float*)d_in[4], r_dt_w,
                                     (const float*)d_in[14], l_dt_w, wxpc);
  prep_cw<<<41, 256, 0, stream>>>(dw_w, r_conv_w, l_conv_w, cwt);
  const float* dwt  = cwt;
  const float* rcwt = cwt + 6912;
  const float* lcwt = cwt + 9984;

  // 1. LayerNorm (bf16 out)
  ln_kernel<<<dim3(256), dim3(256), 0, stream>>>(x, ln_g, ln_b, xnbf);

  // 2. Region branch (natural order)
  const ushortT* w_in  = wbf;
  const ushortT* w_out = wbf + 328704;
  // in-proj: BM=128, 512 threads, grid 512 = 2 blocks/CU, 16 waves/CU
  gemm_mfma<5,128,0,512><<<512, 512, 0, stream>>>(xnbf, w_in, nullptr, xs4, zbf,
                                                  16384, 1536, 192, 4, 6, 512, 0, 0, 0, 0, 0);
  conv_region_k8<<<6144, 256, 0, stream>>>(xs4, rcwt, r_conv_b, xcbf, 4 * nBLC8);
  // xproj+dt: BM=64, 256 threads, grid 2048 (best measured config)
  gemm_mfma<3,64,0,256><<<2048, 256, 0, stream>>>(xcbf, wxpc, r_dt_b, ddb, dtvbf,
                                                  16384, 224, 192, 2, 2, 512, BLC, 43008,
                                                  524288, 3145728, 32);
  scanA_r<<<2048, 192, 0, stream>>>(xcbf, ddb, dtvbf, r_Alog, Pcb, Hcb);
  combine_r<<<192, 256, 0, stream>>>(Pcb, Hcb);
  scanC_r<<<2048, 192, 0, stream>>>(xcbf, ddb, dtvbf, zbf, Pcb, r_Alog, r_D);
  gemm_mfma<7,64,1,256><<<768, 256, 0, stream>>>(zbf, w_out, scale_mod, fusedb, nullptr,
                                                 16384, 192, 768, 3, 1, 768, BLC, 36864, 0, 0, 0);

  // 3. Local windowed branch
  const ushortT* wl_in  = wbf + 476160;
  const ushortT* wl_out = wbf + 555264;
  const ushortT* wxpc_l = wxpc + 172032;
  gemm_mfma<2,64,0,256><<<512, 256, 0, stream>>>(xnbf, wl_in, nullptr, xsbf, zbf,
                                                 16384, 384, 192, 2, 3, 512, 0, 0, 0, 0, 0);
  conv_local_k8<<<gs(BLC / 8), 256, 0, stream>>>(xsbf, lcwt, l_conv_b, xcbf, nBLC8);
  gemm_mfma<3,64,0,256><<<512, 256, 0, stream>>>(xcbf, wxpc_l, l_dt_b, ddb, dtvbf,
                                                 16384, 208, 192, 2, 2, 512, 0, 0, 0, 0, 16);
  scanA_l<<<1024, 192, 0, stream>>>(xcbf, ddb, dtvbf, l_Alog, Pl, Hl);
  combine_l<<<1536, 256, 0, stream>>>(Pl, Hl);
  scanC_l<<<1024, 192, 0, stream>>>(xcbf, ddb, dtvbf, zbf, Pl, l_Alog, l_D);
  gemm_mfma<6,64,0,256><<<768, 256, 0, stream>>>(zbf, wl_out, nullptr, fusedb, nullptr,
                                                 16384, 192, 192, 3, 1, 768, 0, 0, 0, 0, 0);

  // 4. SGFN + final residual
  const ushortT* w_c1 = wbf + 592128;
  const ushortT* w_c2 = wbf + 739584;
  gemm_mfma<1,64,0,256><<<768, 256, 0, stream>>>(fusedb, w_c1, c1_b, h1, nullptr,
                                                 16384, 768, 192, 3, 4, 768, 0, 0, 0, 0, 0);
  dwglu_k<<<1024, 192, 0, stream>>>(h1, dwt, dw_b, glu);
  gemm_mfma<0,64,0,256><<<768, 256, 0, stream>>>(glu, w_c2, c2_b, sgout, nullptr,
                                                 16384, 192, 384, 3, 1, 768, 0, 0, 0, 0, 0);
  final_k_t<<<256, 256, 0, stream>>>(x, fusedb, sgout, gamma, out);
}